// Round 7
// baseline (238.103 us; speedup 1.0000x reference)
//
#include <hip/hip_runtime.h>
#include <hip/hip_bf16.h>
#include <cstdint>
#include <cstddef>

#define D_MODEL 1024
#define NHEADS  16
#define HDIM    64
#define HALFW   32
#define BATCH   4
#define SEQ     4096
#define MROWS   (BATCH*SEQ)

typedef __attribute__((ext_vector_type(8))) short        bf16x8;
typedef __attribute__((ext_vector_type(4))) float        f32x4;
typedef __attribute__((ext_vector_type(4))) unsigned int u32x4;

typedef const __attribute__((address_space(1))) void gvoid_t;
typedef __attribute__((address_space(3))) void       lvoid_t;

__device__ __forceinline__ unsigned short f2bf(float f) {
    unsigned int u = __float_as_uint(f);
    u += 0x7fffu + ((u >> 16) & 1u);   // RNE
    return (unsigned short)(u >> 16);
}

// XOR swizzle for row-major [R][128] bf16 LDS tiles (256B rows) - attn kernel.
__device__ __forceinline__ int vswz(int row, int bytecol) {
    return (row * 256 + bytecol) ^ (((row ^ (row >> 3)) & 7) << 4);
}

// ---------------- f32 -> bf16 conversion (vectorized, 8 elems/thread) ----------
__global__ __launch_bounds__(256)
void cvt_f32_bf16(const float* __restrict__ src, unsigned short* __restrict__ dst, int n8) {
    int i = blockIdx.x * 256 + threadIdx.x;
    if (i >= n8) return;
    float4 a = *(const float4*)(src + (size_t)i * 8);
    float4 b = *(const float4*)(src + (size_t)i * 8 + 4);
    u32x4 o;
    o[0] = (unsigned)f2bf(a.x) | ((unsigned)f2bf(a.y) << 16);
    o[1] = (unsigned)f2bf(a.z) | ((unsigned)f2bf(a.w) << 16);
    o[2] = (unsigned)f2bf(b.x) | ((unsigned)f2bf(b.y) << 16);
    o[3] = (unsigned)f2bf(b.z) | ((unsigned)f2bf(b.w) << 16);
    *(u32x4*)(dst + (size_t)i * 8) = o;
}

__global__ __launch_bounds__(256)
void cvt4_f32_bf16(const float* __restrict__ s0, const float* __restrict__ s1,
                   const float* __restrict__ s2, const float* __restrict__ s3,
                   unsigned short* __restrict__ d0, unsigned short* __restrict__ d1,
                   unsigned short* __restrict__ d2, unsigned short* __restrict__ d3, int n8) {
    int i = blockIdx.x * 256 + threadIdx.x;
    if (i >= n8) return;
    const float* src = blockIdx.y == 0 ? s0 : blockIdx.y == 1 ? s1 : blockIdx.y == 2 ? s2 : s3;
    unsigned short* dst = blockIdx.y == 0 ? d0 : blockIdx.y == 1 ? d1 : blockIdx.y == 2 ? d2 : d3;
    float4 a = *(const float4*)(src + (size_t)i * 8);
    float4 b = *(const float4*)(src + (size_t)i * 8 + 4);
    u32x4 o;
    o[0] = (unsigned)f2bf(a.x) | ((unsigned)f2bf(a.y) << 16);
    o[1] = (unsigned)f2bf(a.z) | ((unsigned)f2bf(a.w) << 16);
    o[2] = (unsigned)f2bf(b.x) | ((unsigned)f2bf(b.y) << 16);
    o[3] = (unsigned)f2bf(b.z) | ((unsigned)f2bf(b.w) << 16);
    *(u32x4*)(dst + (size_t)i * 8) = o;
}

// ------------- 256x256 8-phase bf16 GEMM (B^T), 8 waves, BK=64 ---------------
// m201-faithful schedule at half-tile granularity. Half-tile h = K-half of
// tile h>>1 (16KB per matrix). Ring = 4 slots (2 K-tiles). Pair hp consumes
// half-tile hp and stages hp+3 (A in even phase, B in odd). 3 half-tiles in
// flight; vmcnt(8) once per pair (ladder 4/0 at the tail). ds_reads issued
// BEFORE s_barrier, waited AFTER with lgkmcnt(0); sched_barrier(0) pins order.
// LDS chunk swizzle: chunk c of row r at position (c+(r>>1))&3 -> conflict-free.
template <int NOUT, int F32OUT>
__global__ __launch_bounds__(512)
void gemm256(const unsigned short* __restrict__ A,
             const unsigned short* __restrict__ W0,
             const unsigned short* __restrict__ W1,
             const unsigned short* __restrict__ W2,
             const float* __restrict__ b0, const float* __restrict__ b1,
             const float* __restrict__ b2,
             unsigned short* __restrict__ o0, unsigned short* __restrict__ o1,
             unsigned short* __restrict__ o2, float* __restrict__ of32)
{
    constexpr int K  = 1024;
    constexpr int HT = K / 32;                 // 32 half-tiles of 32-k
    constexpr int NWG = 64 * 4 * NOUT;
    __shared__ unsigned short lds[65536];      // A ring 64KB + B ring 64KB

    const int tid  = threadIdx.x;
    const int wave = tid >> 6, lane = tid & 63;
    const int wr = wave >> 2, wc = wave & 3;   // 2x4 wave grid; per-wave 128x64

    const int bid = blockIdx.x;
    const int g   = (bid & 7) * (NWG / 8) + (bid >> 3);
    const int rb  = g / (4 * NOUT);
    const int cb  = g % (4 * NOUT);
    const int which = cb >> 2;
    const int bm = rb * 256, bn = (cb & 3) * 256;

    const unsigned short* W = (NOUT == 1 || which == 0) ? W0 : (which == 1 ? W1 : W2);
    const float* bias       = (NOUT == 1 || which == 0) ? b0 : (which == 1 ? b1 : b2);
    unsigned short* obf     = (NOUT == 1 || which == 0) ? o0 : (which == 1 ? o1 : o2);

    f32x4 acc[8][4];
    #pragma unroll
    for (int m = 0; m < 8; ++m)
        #pragma unroll
        for (int n = 0; n < 4; ++n)
            #pragma unroll
            for (int j = 0; j < 4; ++j) acc[m][n][j] = 0.0f;

    char* ldsb = (char*)lds;

    // staging addresses: half-tile (16KB/matrix) = 2 loads x 512 thr x 16B
    const int idx0 = tid, idx1 = tid + 512;
    const int r0 = idx0 >> 2, r1 = idx1 >> 2;
    const int c0 = ((idx0 & 3) - (r0 >> 1)) & 3;
    const int c1 = ((idx1 & 3) - (r1 >> 1)) & 3;
    const size_t sA0 = (size_t)(bm + r0) * K + c0 * 8;
    const size_t sA1 = (size_t)(bm + r1) * K + c1 * 8;
    const size_t sB0 = (size_t)(bn + r0) * K + c0 * 8;
    const size_t sB1 = (size_t)(bn + r1) * K + c1 * 8;
    const int ldsW = wave * 1024;              // wave-uniform base (+lane*16 by HW)

    auto STAGE = [&](int h, int isA) {
        const int base = (isA ? 0 : 65536) + (h & 3) * 16384 + ldsW;
        const int ke = h * 32;
        const unsigned short* M = isA ? A : W;
        const size_t s0 = isA ? sA0 : sB0;
        const size_t s1 = isA ? sA1 : sB1;
        __builtin_amdgcn_global_load_lds((gvoid_t*)(M + s0 + ke),
            (lvoid_t*)(ldsb + base), 16, 0, 0);
        __builtin_amdgcn_global_load_lds((gvoid_t*)(M + s1 + ke),
            (lvoid_t*)(ldsb + base + 8192), 16, 0, 0);
    };

    // fragment read bases
    const int lr = lane & 15;
    const int pp = (((lane >> 4) + (lr >> 1)) & 3) << 4;       // swizzled chunk pos
    const int abase = (wr * 128 + lr) * 64 + pp;               // + slot*16384 + mi*1024
    const int bbase = 65536 + (wc * 64 + lr) * 64 + pp;        // + slot*16384 + ni*1024

    // prologue: stage half-tiles 0,1,2; wait h0 landed (8 = h1,h2 outstanding)
    STAGE(0, 1); STAGE(0, 0); STAGE(1, 1); STAGE(1, 0); STAGE(2, 1); STAGE(2, 0);
    asm volatile("s_waitcnt vmcnt(8)" ::: "memory");
    __builtin_amdgcn_s_barrier();

    #pragma unroll 1
    for (int hp = 0; hp < HT; ++hp) {
        const int so = (hp & 3) * 16384;
        bf16x8 aL[4], bb[4], aH[4];
        // ================= even phase: reads A0-3 + B0-3, stage A(h+3) ======
        #pragma unroll
        for (int m = 0; m < 4; ++m) aL[m] = *(const bf16x8*)(ldsb + so + abase + m * 1024);
        #pragma unroll
        for (int n = 0; n < 4; ++n) bb[n] = *(const bf16x8*)(ldsb + so + bbase + n * 1024);
        __builtin_amdgcn_sched_barrier(0);
        if (hp + 3 < HT) STAGE(hp + 3, 1);
        __builtin_amdgcn_sched_barrier(0);
        __builtin_amdgcn_s_barrier();
        asm volatile("s_waitcnt lgkmcnt(0)" ::: "memory");
        __builtin_amdgcn_sched_barrier(0);
        __builtin_amdgcn_s_setprio(1);
        #pragma unroll
        for (int m = 0; m < 4; ++m)
            #pragma unroll
            for (int n = 0; n < 4; ++n)
                acc[m][n] = __builtin_amdgcn_mfma_f32_16x16x32_bf16(aL[m], bb[n], acc[m][n], 0, 0, 0);
        __builtin_amdgcn_s_setprio(0);
        __builtin_amdgcn_sched_barrier(0);
        __builtin_amdgcn_s_barrier();
        // ================= odd phase: reads A4-7, stage B(h+3), vmcnt =======
        #pragma unroll
        for (int m = 0; m < 4; ++m) aH[m] = *(const bf16x8*)(ldsb + so + abase + (m + 4) * 1024);
        __builtin_amdgcn_sched_barrier(0);
        if (hp + 3 < HT) STAGE(hp + 3, 0);
        if (hp <= HT - 4)      { asm volatile("s_waitcnt vmcnt(8)" ::: "memory"); }
        else if (hp == HT - 3) { asm volatile("s_waitcnt vmcnt(4)" ::: "memory"); }
        else if (hp == HT - 2) { asm volatile("s_waitcnt vmcnt(0)" ::: "memory"); }
        __builtin_amdgcn_sched_barrier(0);
        __builtin_amdgcn_s_barrier();
        asm volatile("s_waitcnt lgkmcnt(0)" ::: "memory");
        __builtin_amdgcn_sched_barrier(0);
        __builtin_amdgcn_s_setprio(1);
        #pragma unroll
        for (int m = 0; m < 4; ++m)
            #pragma unroll
            for (int n = 0; n < 4; ++n)
                acc[m + 4][n] = __builtin_amdgcn_mfma_f32_16x16x32_bf16(aH[m], bb[n], acc[m + 4][n], 0, 0, 0);
        __builtin_amdgcn_s_setprio(0);
        __builtin_amdgcn_sched_barrier(0);
        __builtin_amdgcn_s_barrier();
    }

    // epilogue: bias + store, n innermost (full 128B lines per 16-lane group)
    float bvv[4];
    #pragma unroll
    for (int n = 0; n < 4; ++n) bvv[n] = bias[bn + wc * 64 + n * 16 + lr];
    #pragma unroll
    for (int m = 0; m < 8; ++m) {
        #pragma unroll
        for (int j = 0; j < 4; ++j) {
            const int row = bm + wr * 128 + m * 16 + (lane >> 4) * 4 + j;
            #pragma unroll
            for (int n = 0; n < 4; ++n) {
                const int col = bn + wc * 64 + n * 16 + lr;
                const float v = acc[m][n][j] + bvv[n];
                if (F32OUT) of32[(size_t)row * 1024 + col] = v;
                else        obf[(size_t)row * 1024 + col]  = f2bf(v);
            }
        }
    }
}

// ---------------- banded attention: one block per (b, h, 64-query tile) --------
__global__ __launch_bounds__(256)
void attn_band(const unsigned short* __restrict__ Q,
               const unsigned short* __restrict__ Kk,
               const unsigned short* __restrict__ V,
               unsigned short* __restrict__ Ctx)
{
    __shared__ unsigned short Qs[64 * 72];
    __shared__ unsigned short Ks[128 * 72];
    __shared__ unsigned short Vt[64 * 128];
    __shared__ unsigned short Ps[64 * 128];

    const int qt = blockIdx.x, h = blockIdx.y, b = blockIdx.z;
    const int qbase  = qt * 64;
    const int kstart = qbase - HALFW;
    const int tid = threadIdx.x, wave = tid >> 6, lane = tid & 63;

    const size_t base = (size_t)b * SEQ * D_MODEL + (size_t)h * HDIM;
    const unsigned short* Qb = Q  + base;
    const unsigned short* Kb = Kk + base;
    const unsigned short* Vb = V  + base;
    unsigned short*       Cb = Ctx + base;

    for (int c = tid; c < 512; c += 256) {
        const int row = c >> 3, col = (c & 7) * 8;
        *(u32x4*)(Qs + row * 72 + col) =
            *(const u32x4*)(Qb + (size_t)(qbase + row) * D_MODEL + col);
    }
    for (int c = tid; c < 1024; c += 256) {
        const int krow = c >> 3, col = (c & 7) * 8;
        const int kpos = kstart + krow;
        u32x4 kv;
        if (kpos >= 0 && kpos < SEQ) {
            kv = *(const u32x4*)(Kb + (size_t)kpos * D_MODEL + col);
        } else {
            for (int j = 0; j < 4; ++j) kv[j] = 0u;
        }
        *(u32x4*)(Ks + krow * 72 + col) = kv;
    }
    for (int c = tid; c < 512; c += 256) {
        const int p = c >> 3, dch = c & 7;
        const int k0 = kstart + 2 * p, k1 = k0 + 1;
        u32x4 v0, v1;
        if (k0 >= 0 && k0 < SEQ) {
            v0 = *(const u32x4*)(Vb + (size_t)k0 * D_MODEL + dch * 8);
        } else {
            for (int j = 0; j < 4; ++j) v0[j] = 0u;
        }
        if (k1 >= 0 && k1 < SEQ) {
            v1 = *(const u32x4*)(Vb + (size_t)k1 * D_MODEL + dch * 8);
        } else {
            for (int j = 0; j < 4; ++j) v1[j] = 0u;
        }
        #pragma unroll
        for (int j = 0; j < 8; ++j) {
            const int d = dch * 8 + j;
            const unsigned lo = (v0[j >> 1] >> ((j & 1) * 16)) & 0xffffu;
            const unsigned hi = (v1[j >> 1] >> ((j & 1) * 16)) & 0xffffu;
            *(unsigned*)((char*)Vt + vswz(d, 4 * p)) = lo | (hi << 16);
        }
    }
    __syncthreads();

    f32x4 sc[8];
    #pragma unroll
    for (int c = 0; c < 8; ++c)
        #pragma unroll
        for (int j = 0; j < 4; ++j) sc[c][j] = 0.0f;

    bf16x8 aq[2];
    #pragma unroll
    for (int kc = 0; kc < 2; ++kc)
        aq[kc] = *(const bf16x8*)(Qs + (wave * 16 + (lane & 15)) * 72 + kc * 32 + (lane >> 4) * 8);
    #pragma unroll
    for (int c = 0; c < 8; ++c) {
        #pragma unroll
        for (int kc = 0; kc < 2; ++kc) {
            bf16x8 bk_ = *(const bf16x8*)(Ks + (c * 16 + (lane & 15)) * 72 + kc * 32 + (lane >> 4) * 8);
            sc[c] = __builtin_amdgcn_mfma_f32_16x16x32_bf16(aq[kc], bk_, sc[c], 0, 0, 0);
        }
    }

    const int grp = lane >> 4, colk = lane & 15;
    float rowmax[4] = {-1e30f, -1e30f, -1e30f, -1e30f};
    #pragma unroll
    for (int c = 0; c < 8; ++c) {
        const int kpos = kstart + c * 16 + colk;
        #pragma unroll
        for (int j = 0; j < 4; ++j) {
            const int qpos = qbase + wave * 16 + grp * 4 + j;
            const int rel = kpos - qpos;
            const bool valid = (kpos >= 0) && (kpos < SEQ) && (rel >= -HALFW) && (rel <= HALFW);
            const float v = valid ? sc[c][j] * 0.125f : -1e30f;
            sc[c][j] = v;
            rowmax[j] = fmaxf(rowmax[j], v);
        }
    }
    #pragma unroll
    for (int j = 0; j < 4; ++j)
        #pragma unroll
        for (int m = 1; m < 16; m <<= 1)
            rowmax[j] = fmaxf(rowmax[j], __shfl_xor(rowmax[j], m, 64));

    float rowsum[4] = {0.f, 0.f, 0.f, 0.f};
    #pragma unroll
    for (int c = 0; c < 8; ++c)
        #pragma unroll
        for (int j = 0; j < 4; ++j) {
            const float p = __expf(sc[c][j] - rowmax[j]);
            sc[c][j] = p;
            rowsum[j] += p;
        }
    #pragma unroll
    for (int j = 0; j < 4; ++j)
        #pragma unroll
        for (int m = 1; m < 16; m <<= 1)
            rowsum[j] += __shfl_xor(rowsum[j], m, 64);

    #pragma unroll
    for (int c = 0; c < 8; ++c)
        #pragma unroll
        for (int j = 0; j < 4; ++j)
            *(unsigned short*)((char*)Ps + vswz(wave * 16 + grp * 4 + j, (c * 16 + colk) * 2))
                = f2bf(sc[c][j]);
    __syncthreads();

    f32x4 o[4];
    #pragma unroll
    for (int n = 0; n < 4; ++n)
        #pragma unroll
        for (int j = 0; j < 4; ++j) o[n][j] = 0.0f;
    #pragma unroll
    for (int kc = 0; kc < 4; ++kc) {
        bf16x8 pa = *(const bf16x8*)((const char*)Ps +
                        vswz(wave * 16 + (lane & 15), kc * 64 + (lane >> 4) * 16));
        #pragma unroll
        for (int n = 0; n < 4; ++n) {
            bf16x8 bv_ = *(const bf16x8*)((const char*)Vt +
                            vswz(n * 16 + (lane & 15), kc * 64 + (lane >> 4) * 16));
            o[n] = __builtin_amdgcn_mfma_f32_16x16x32_bf16(pa, bv_, o[n], 0, 0, 0);
        }
    }

    float rinv[4];
    #pragma unroll
    for (int j = 0; j < 4; ++j) rinv[j] = 1.0f / rowsum[j];
    #pragma unroll
    for (int n = 0; n < 4; ++n)
        #pragma unroll
        for (int j = 0; j < 4; ++j) {
            const int q = qbase + wave * 16 + grp * 4 + j;
            Cb[(size_t)q * D_MODEL + n * 16 + colk] = f2bf(o[n][j] * rinv[j]);
        }
}

// ------------------------------------------------------------------------------
extern "C" void kernel_launch(void* const* d_in, const int* in_sizes, int n_in,
                              void* d_out, int out_size, void* d_ws, size_t ws_size,
                              hipStream_t stream)
{
    (void)in_sizes; (void)n_in; (void)out_size; (void)ws_size;
    const float* x  = (const float*)d_in[0];
    const float* Wq = (const float*)d_in[1];
    const float* bq = (const float*)d_in[2];
    const float* Wk = (const float*)d_in[3];
    const float* bk = (const float*)d_in[4];
    const float* Wv = (const float*)d_in[5];
    const float* bv = (const float*)d_in[6];
    const float* Wo = (const float*)d_in[7];
    const float* bo = (const float*)d_in[8];
    float* out = (float*)d_out;

    char* ws = (char*)d_ws;
    unsigned short* xb  = (unsigned short*)ws;
    unsigned short* wqb = (unsigned short*)(ws + 33554432);
    unsigned short* wkb = wqb + 1048576;
    unsigned short* wvb = wkb + 1048576;
    unsigned short* wob = wvb + 1048576;
    unsigned short* qb  = wob + 1048576;
    unsigned short* kb  = qb + (size_t)MROWS * D_MODEL;
    unsigned short* vb  = kb + (size_t)MROWS * D_MODEL;
    unsigned short* ctxb = xb;   // alias: x no longer needed after QKV GEMM

    cvt_f32_bf16<<<dim3(MROWS * D_MODEL / 8 / 256), 256, 0, stream>>>(x, xb, MROWS * D_MODEL / 8);
    cvt4_f32_bf16<<<dim3(D_MODEL * D_MODEL / 8 / 256, 4), 256, 0, stream>>>(
        Wq, Wk, Wv, Wo, wqb, wkb, wvb, wob, D_MODEL * D_MODEL / 8);

    // fused QKV: 64 row-blocks x 12 col-blocks (256^2 tiles)
    gemm256<3, 0><<<dim3(768), 512, 0, stream>>>(
        xb, wqb, wkb, wvb, bq, bk, bv, qb, kb, vb, nullptr);

    attn_band<<<dim3(SEQ / 64, NHEADS, BATCH), 256, 0, stream>>>(qb, kb, vb, ctxb);

    gemm256<1, 1><<<dim3(256), 512, 0, stream>>>(
        ctxb, wob, wob, wob, bo, bo, bo, nullptr, nullptr, nullptr, out);
}

// Round 8
// 231.420 us; speedup vs baseline: 1.0289x; 1.0289x over previous
//
#include <hip/hip_runtime.h>
#include <hip/hip_bf16.h>
#include <cstdint>
#include <cstddef>

#define D_MODEL 1024
#define NHEADS  16
#define HDIM    64
#define HALFW   32
#define BATCH   4
#define SEQ     4096
#define MROWS   (BATCH*SEQ)

typedef __attribute__((ext_vector_type(8))) short        bf16x8;
typedef __attribute__((ext_vector_type(4))) float        f32x4;
typedef __attribute__((ext_vector_type(4))) unsigned int u32x4;

typedef const __attribute__((address_space(1))) void gvoid_t;
typedef __attribute__((address_space(3))) void       lvoid_t;

__device__ __forceinline__ unsigned short f2bf(float f) {
    unsigned int u = __float_as_uint(f);
    u += 0x7fffu + ((u >> 16) & 1u);   // RNE
    return (unsigned short)(u >> 16);
}

// XOR swizzle for row-major [R][128] bf16 LDS tiles (256B rows) - attn kernel.
__device__ __forceinline__ int vswz(int row, int bytecol) {
    return (row * 256 + bytecol) ^ (((row ^ (row >> 3)) & 7) << 4);
}

// ---------------- f32 -> bf16 conversion (vectorized, 8 elems/thread) ----------
__global__ __launch_bounds__(256)
void cvt_f32_bf16(const float* __restrict__ src, unsigned short* __restrict__ dst, int n8) {
    int i = blockIdx.x * 256 + threadIdx.x;
    if (i >= n8) return;
    float4 a = *(const float4*)(src + (size_t)i * 8);
    float4 b = *(const float4*)(src + (size_t)i * 8 + 4);
    u32x4 o;
    o[0] = (unsigned)f2bf(a.x) | ((unsigned)f2bf(a.y) << 16);
    o[1] = (unsigned)f2bf(a.z) | ((unsigned)f2bf(a.w) << 16);
    o[2] = (unsigned)f2bf(b.x) | ((unsigned)f2bf(b.y) << 16);
    o[3] = (unsigned)f2bf(b.z) | ((unsigned)f2bf(b.w) << 16);
    *(u32x4*)(dst + (size_t)i * 8) = o;
}

__global__ __launch_bounds__(256)
void cvt4_f32_bf16(const float* __restrict__ s0, const float* __restrict__ s1,
                   const float* __restrict__ s2, const float* __restrict__ s3,
                   unsigned short* __restrict__ d0, unsigned short* __restrict__ d1,
                   unsigned short* __restrict__ d2, unsigned short* __restrict__ d3, int n8) {
    int i = blockIdx.x * 256 + threadIdx.x;
    if (i >= n8) return;
    const float* src = blockIdx.y == 0 ? s0 : blockIdx.y == 1 ? s1 : blockIdx.y == 2 ? s2 : s3;
    unsigned short* dst = blockIdx.y == 0 ? d0 : blockIdx.y == 1 ? d1 : blockIdx.y == 2 ? d2 : d3;
    float4 a = *(const float4*)(src + (size_t)i * 8);
    float4 b = *(const float4*)(src + (size_t)i * 8 + 4);
    u32x4 o;
    o[0] = (unsigned)f2bf(a.x) | ((unsigned)f2bf(a.y) << 16);
    o[1] = (unsigned)f2bf(a.z) | ((unsigned)f2bf(a.w) << 16);
    o[2] = (unsigned)f2bf(b.x) | ((unsigned)f2bf(b.y) << 16);
    o[3] = (unsigned)f2bf(b.z) | ((unsigned)f2bf(b.w) << 16);
    *(u32x4*)(dst + (size_t)i * 8) = o;
}

// ------- 256x256 wave-staggered bf16 GEMM (B^T), 8 waves, half-tile=32k ------
// Ring: 4 slots x 16KB per matrix. Waves 0-3 (X, rows 0-127) and 4-7 (Y, rows
// 128-255) run the same barriers but staggered roles:
//   S1: X ds_read(hp)               | Y MFMA(hp-1) (regs from prev S2)
//   S2: stage(hp+3) A+B; X MFMA(hp) | Y ds_read(hp); vmcnt ladder
// Each SIMD hosts one X and one Y wave -> MFMA pipe busy in BOTH segments.
// Slot-overwrite safety: stage(hp+3) in S2 targets slot (hp-1)&3; its readers'
// lgkmcnt(0) completion is published by the barrier that closed S1(hp).
// LDS chunk swizzle: chunk c of row r at position (c+(r>>1))&3 -> conflict-free.
template <int NOUT, int F32OUT>
__global__ __launch_bounds__(512)
void gemm256(const unsigned short* __restrict__ A,
             const unsigned short* __restrict__ W0,
             const unsigned short* __restrict__ W1,
             const unsigned short* __restrict__ W2,
             const float* __restrict__ b0, const float* __restrict__ b1,
             const float* __restrict__ b2,
             unsigned short* __restrict__ o0, unsigned short* __restrict__ o1,
             unsigned short* __restrict__ o2, float* __restrict__ of32)
{
    constexpr int K  = 1024;
    constexpr int HT = K / 32;                 // 32 half-tiles of 32-k
    constexpr int NWG = 64 * 4 * NOUT;
    __shared__ unsigned short lds[65536];      // A ring 64KB + B ring 64KB

    const int tid  = threadIdx.x;
    const int wave = tid >> 6, lane = tid & 63;
    const int wr = wave >> 2, wc = wave & 3;   // 2x4 wave grid; per-wave 128x64
    const bool isX = (wr == 0);

    const int bid = blockIdx.x;
    const int g   = (bid & 7) * (NWG / 8) + (bid >> 3);
    const int rb  = g / (4 * NOUT);
    const int cb  = g % (4 * NOUT);
    const int which = cb >> 2;
    const int bm = rb * 256, bn = (cb & 3) * 256;

    const unsigned short* W = (NOUT == 1 || which == 0) ? W0 : (which == 1 ? W1 : W2);
    const float* bias       = (NOUT == 1 || which == 0) ? b0 : (which == 1 ? b1 : b2);
    unsigned short* obf     = (NOUT == 1 || which == 0) ? o0 : (which == 1 ? o1 : o2);

    f32x4 acc[8][4];
    #pragma unroll
    for (int m = 0; m < 8; ++m)
        #pragma unroll
        for (int n = 0; n < 4; ++n)
            #pragma unroll
            for (int j = 0; j < 4; ++j) acc[m][n][j] = 0.0f;

    char* ldsb = (char*)lds;

    // staging addresses: half-tile (16KB/matrix) = 2 loads x 512 thr x 16B
    const int idx0 = tid, idx1 = tid + 512;
    const int r0 = idx0 >> 2, r1 = idx1 >> 2;
    const int c0 = ((idx0 & 3) - (r0 >> 1)) & 3;
    const int c1 = ((idx1 & 3) - (r1 >> 1)) & 3;
    const size_t sA0 = (size_t)(bm + r0) * K + c0 * 8;
    const size_t sA1 = (size_t)(bm + r1) * K + c1 * 8;
    const size_t sB0 = (size_t)(bn + r0) * K + c0 * 8;
    const size_t sB1 = (size_t)(bn + r1) * K + c1 * 8;
    const int ldsW = wave * 1024;              // wave-uniform base (+lane*16 by HW)

    auto STAGE = [&](int h, int isA) {
        const int base = (isA ? 0 : 65536) + (h & 3) * 16384 + ldsW;
        const int ke = h * 32;
        const unsigned short* M = isA ? A : W;
        const size_t s0 = isA ? sA0 : sB0;
        const size_t s1 = isA ? sA1 : sB1;
        __builtin_amdgcn_global_load_lds((gvoid_t*)(M + s0 + ke),
            (lvoid_t*)(ldsb + base), 16, 0, 0);
        __builtin_amdgcn_global_load_lds((gvoid_t*)(M + s1 + ke),
            (lvoid_t*)(ldsb + base + 8192), 16, 0, 0);
    };

    // fragment read bases
    const int lr = lane & 15;
    const int pp = (((lane >> 4) + (lr >> 1)) & 3) << 4;       // swizzled chunk pos
    const int abase = (wr * 128 + lr) * 64 + pp;               // + slot*16384 + mi*1024
    const int bbase = 65536 + (wc * 64 + lr) * 64 + pp;        // + slot*16384 + ni*1024

    // prologue: stage half-tiles 0,1,2; wait h0 landed (8 = h1,h2 outstanding)
    STAGE(0, 1); STAGE(0, 0); STAGE(1, 1); STAGE(1, 0); STAGE(2, 1); STAGE(2, 0);
    asm volatile("s_waitcnt vmcnt(8)" ::: "memory");
    __builtin_amdgcn_s_barrier();

    bf16x8 fa[8], fb[4];

    #pragma unroll 1
    for (int hp = 0; hp < HT; ++hp) {
        const int so = (hp & 3) * 16384;
        // ---------------- S1: X reads(hp) | Y MFMA(hp-1) --------------------
        if (isX) {
            #pragma unroll
            for (int m = 0; m < 8; ++m) fa[m] = *(const bf16x8*)(ldsb + so + abase + m * 1024);
            #pragma unroll
            for (int n = 0; n < 4; ++n) fb[n] = *(const bf16x8*)(ldsb + so + bbase + n * 1024);
        } else if (hp > 0) {
            asm volatile("s_waitcnt lgkmcnt(0)" ::: "memory");
            __builtin_amdgcn_sched_barrier(0);
            __builtin_amdgcn_s_setprio(1);
            #pragma unroll
            for (int m = 0; m < 8; ++m)
                #pragma unroll
                for (int n = 0; n < 4; ++n)
                    acc[m][n] = __builtin_amdgcn_mfma_f32_16x16x32_bf16(fa[m], fb[n], acc[m][n], 0, 0, 0);
            __builtin_amdgcn_s_setprio(0);
        }
        __builtin_amdgcn_sched_barrier(0);
        __builtin_amdgcn_s_barrier();
        // ---------------- S2: stage(hp+3); X MFMA(hp) | Y reads(hp) ---------
        if (hp + 3 < HT) { STAGE(hp + 3, 1); STAGE(hp + 3, 0); }
        __builtin_amdgcn_sched_barrier(0);
        if (isX) {
            asm volatile("s_waitcnt lgkmcnt(0)" ::: "memory");
            __builtin_amdgcn_sched_barrier(0);
            __builtin_amdgcn_s_setprio(1);
            #pragma unroll
            for (int m = 0; m < 8; ++m)
                #pragma unroll
                for (int n = 0; n < 4; ++n)
                    acc[m][n] = __builtin_amdgcn_mfma_f32_16x16x32_bf16(fa[m], fb[n], acc[m][n], 0, 0, 0);
            __builtin_amdgcn_s_setprio(0);
        } else {
            #pragma unroll
            for (int m = 0; m < 8; ++m) fa[m] = *(const bf16x8*)(ldsb + so + abase + m * 1024);
            #pragma unroll
            for (int n = 0; n < 4; ++n) fb[n] = *(const bf16x8*)(ldsb + so + bbase + n * 1024);
        }
        __builtin_amdgcn_sched_barrier(0);
        if (hp <= HT - 4)      { asm volatile("s_waitcnt vmcnt(8)" ::: "memory"); }
        else if (hp == HT - 3) { asm volatile("s_waitcnt vmcnt(4)" ::: "memory"); }
        else                   { asm volatile("s_waitcnt vmcnt(0)" ::: "memory"); }
        __builtin_amdgcn_s_barrier();
    }
    // Y tail: consume half-tile HT-1 (read in S2 of last iteration)
    if (!isX) {
        asm volatile("s_waitcnt lgkmcnt(0)" ::: "memory");
        __builtin_amdgcn_sched_barrier(0);
        #pragma unroll
        for (int m = 0; m < 8; ++m)
            #pragma unroll
            for (int n = 0; n < 4; ++n)
                acc[m][n] = __builtin_amdgcn_mfma_f32_16x16x32_bf16(fa[m], fb[n], acc[m][n], 0, 0, 0);
    }

    // epilogue: bias + store, n innermost (full 128B lines per 16-lane group)
    float bvv[4];
    #pragma unroll
    for (int n = 0; n < 4; ++n) bvv[n] = bias[bn + wc * 64 + n * 16 + lr];
    #pragma unroll
    for (int m = 0; m < 8; ++m) {
        #pragma unroll
        for (int j = 0; j < 4; ++j) {
            const int row = bm + wr * 128 + m * 16 + (lane >> 4) * 4 + j;
            #pragma unroll
            for (int n = 0; n < 4; ++n) {
                const int col = bn + wc * 64 + n * 16 + lr;
                const float v = acc[m][n][j] + bvv[n];
                if (F32OUT) of32[(size_t)row * 1024 + col] = v;
                else        obf[(size_t)row * 1024 + col]  = f2bf(v);
            }
        }
    }
}

// ---------------- banded attention: one block per (b, h, 64-query tile) --------
__global__ __launch_bounds__(256)
void attn_band(const unsigned short* __restrict__ Q,
               const unsigned short* __restrict__ Kk,
               const unsigned short* __restrict__ V,
               unsigned short* __restrict__ Ctx)
{
    __shared__ unsigned short Qs[64 * 72];
    __shared__ unsigned short Ks[128 * 72];
    __shared__ unsigned short Vt[64 * 128];
    __shared__ unsigned short Ps[64 * 128];

    const int qt = blockIdx.x, h = blockIdx.y, b = blockIdx.z;
    const int qbase  = qt * 64;
    const int kstart = qbase - HALFW;
    const int tid = threadIdx.x, wave = tid >> 6, lane = tid & 63;

    const size_t base = (size_t)b * SEQ * D_MODEL + (size_t)h * HDIM;
    const unsigned short* Qb = Q  + base;
    const unsigned short* Kb = Kk + base;
    const unsigned short* Vb = V  + base;
    unsigned short*       Cb = Ctx + base;

    for (int c = tid; c < 512; c += 256) {
        const int row = c >> 3, col = (c & 7) * 8;
        *(u32x4*)(Qs + row * 72 + col) =
            *(const u32x4*)(Qb + (size_t)(qbase + row) * D_MODEL + col);
    }
    for (int c = tid; c < 1024; c += 256) {
        const int krow = c >> 3, col = (c & 7) * 8;
        const int kpos = kstart + krow;
        u32x4 kv;
        if (kpos >= 0 && kpos < SEQ) {
            kv = *(const u32x4*)(Kb + (size_t)kpos * D_MODEL + col);
        } else {
            for (int j = 0; j < 4; ++j) kv[j] = 0u;
        }
        *(u32x4*)(Ks + krow * 72 + col) = kv;
    }
    for (int c = tid; c < 512; c += 256) {
        const int p = c >> 3, dch = c & 7;
        const int k0 = kstart + 2 * p, k1 = k0 + 1;
        u32x4 v0, v1;
        if (k0 >= 0 && k0 < SEQ) {
            v0 = *(const u32x4*)(Vb + (size_t)k0 * D_MODEL + dch * 8);
        } else {
            for (int j = 0; j < 4; ++j) v0[j] = 0u;
        }
        if (k1 >= 0 && k1 < SEQ) {
            v1 = *(const u32x4*)(Vb + (size_t)k1 * D_MODEL + dch * 8);
        } else {
            for (int j = 0; j < 4; ++j) v1[j] = 0u;
        }
        #pragma unroll
        for (int j = 0; j < 8; ++j) {
            const int d = dch * 8 + j;
            const unsigned lo = (v0[j >> 1] >> ((j & 1) * 16)) & 0xffffu;
            const unsigned hi = (v1[j >> 1] >> ((j & 1) * 16)) & 0xffffu;
            *(unsigned*)((char*)Vt + vswz(d, 4 * p)) = lo | (hi << 16);
        }
    }
    __syncthreads();

    f32x4 sc[8];
    #pragma unroll
    for (int c = 0; c < 8; ++c)
        #pragma unroll
        for (int j = 0; j < 4; ++j) sc[c][j] = 0.0f;

    bf16x8 aq[2];
    #pragma unroll
    for (int kc = 0; kc < 2; ++kc)
        aq[kc] = *(const bf16x8*)(Qs + (wave * 16 + (lane & 15)) * 72 + kc * 32 + (lane >> 4) * 8);
    #pragma unroll
    for (int c = 0; c < 8; ++c) {
        #pragma unroll
        for (int kc = 0; kc < 2; ++kc) {
            bf16x8 bk_ = *(const bf16x8*)(Ks + (c * 16 + (lane & 15)) * 72 + kc * 32 + (lane >> 4) * 8);
            sc[c] = __builtin_amdgcn_mfma_f32_16x16x32_bf16(aq[kc], bk_, sc[c], 0, 0, 0);
        }
    }

    const int grp = lane >> 4, colk = lane & 15;
    float rowmax[4] = {-1e30f, -1e30f, -1e30f, -1e30f};
    #pragma unroll
    for (int c = 0; c < 8; ++c) {
        const int kpos = kstart + c * 16 + colk;
        #pragma unroll
        for (int j = 0; j < 4; ++j) {
            const int qpos = qbase + wave * 16 + grp * 4 + j;
            const int rel = kpos - qpos;
            const bool valid = (kpos >= 0) && (kpos < SEQ) && (rel >= -HALFW) && (rel <= HALFW);
            const float v = valid ? sc[c][j] * 0.125f : -1e30f;
            sc[c][j] = v;
            rowmax[j] = fmaxf(rowmax[j], v);
        }
    }
    #pragma unroll
    for (int j = 0; j < 4; ++j)
        #pragma unroll
        for (int m = 1; m < 16; m <<= 1)
            rowmax[j] = fmaxf(rowmax[j], __shfl_xor(rowmax[j], m, 64));

    float rowsum[4] = {0.f, 0.f, 0.f, 0.f};
    #pragma unroll
    for (int c = 0; c < 8; ++c)
        #pragma unroll
        for (int j = 0; j < 4; ++j) {
            const float p = __expf(sc[c][j] - rowmax[j]);
            sc[c][j] = p;
            rowsum[j] += p;
        }
    #pragma unroll
    for (int j = 0; j < 4; ++j)
        #pragma unroll
        for (int m = 1; m < 16; m <<= 1)
            rowsum[j] += __shfl_xor(rowsum[j], m, 64);

    #pragma unroll
    for (int c = 0; c < 8; ++c)
        #pragma unroll
        for (int j = 0; j < 4; ++j)
            *(unsigned short*)((char*)Ps + vswz(wave * 16 + grp * 4 + j, (c * 16 + colk) * 2))
                = f2bf(sc[c][j]);
    __syncthreads();

    f32x4 o[4];
    #pragma unroll
    for (int n = 0; n < 4; ++n)
        #pragma unroll
        for (int j = 0; j < 4; ++j) o[n][j] = 0.0f;
    #pragma unroll
    for (int kc = 0; kc < 4; ++kc) {
        bf16x8 pa = *(const bf16x8*)((const char*)Ps +
                        vswz(wave * 16 + (lane & 15), kc * 64 + (lane >> 4) * 16));
        #pragma unroll
        for (int n = 0; n < 4; ++n) {
            bf16x8 bv_ = *(const bf16x8*)((const char*)Vt +
                            vswz(n * 16 + (lane & 15), kc * 64 + (lane >> 4) * 16));
            o[n] = __builtin_amdgcn_mfma_f32_16x16x32_bf16(pa, bv_, o[n], 0, 0, 0);
        }
    }

    float rinv[4];
    #pragma unroll
    for (int j = 0; j < 4; ++j) rinv[j] = 1.0f / rowsum[j];
    #pragma unroll
    for (int n = 0; n < 4; ++n)
        #pragma unroll
        for (int j = 0; j < 4; ++j) {
            const int q = qbase + wave * 16 + grp * 4 + j;
            Cb[(size_t)q * D_MODEL + n * 16 + colk] = f2bf(o[n][j] * rinv[j]);
        }
}

// ------------------------------------------------------------------------------
extern "C" void kernel_launch(void* const* d_in, const int* in_sizes, int n_in,
                              void* d_out, int out_size, void* d_ws, size_t ws_size,
                              hipStream_t stream)
{
    (void)in_sizes; (void)n_in; (void)out_size; (void)ws_size;
    const float* x  = (const float*)d_in[0];
    const float* Wq = (const float*)d_in[1];
    const float* bq = (const float*)d_in[2];
    const float* Wk = (const float*)d_in[3];
    const float* bk = (const float*)d_in[4];
    const float* Wv = (const float*)d_in[5];
    const float* bv = (const float*)d_in[6];
    const float* Wo = (const float*)d_in[7];
    const float* bo = (const float*)d_in[8];
    float* out = (float*)d_out;

    char* ws = (char*)d_ws;
    unsigned short* xb  = (unsigned short*)ws;
    unsigned short* wqb = (unsigned short*)(ws + 33554432);
    unsigned short* wkb = wqb + 1048576;
    unsigned short* wvb = wkb + 1048576;
    unsigned short* wob = wvb + 1048576;
    unsigned short* qb  = wob + 1048576;
    unsigned short* kb  = qb + (size_t)MROWS * D_MODEL;
    unsigned short* vb  = kb + (size_t)MROWS * D_MODEL;
    unsigned short* ctxb = xb;   // alias: x no longer needed after QKV GEMM

    cvt_f32_bf16<<<dim3(MROWS * D_MODEL / 8 / 256), 256, 0, stream>>>(x, xb, MROWS * D_MODEL / 8);
    cvt4_f32_bf16<<<dim3(D_MODEL * D_MODEL / 8 / 256, 4), 256, 0, stream>>>(
        Wq, Wk, Wv, Wo, wqb, wkb, wvb, wob, D_MODEL * D_MODEL / 8);

    // fused QKV: 64 row-blocks x 12 col-blocks (256^2 tiles)
    gemm256<3, 0><<<dim3(768), 512, 0, stream>>>(
        xb, wqb, wkb, wvb, bq, bk, bv, qb, kb, vb, nullptr);

    attn_band<<<dim3(SEQ / 64, NHEADS, BATCH), 256, 0, stream>>>(qb, kb, vb, ctxb);

    gemm256<1, 1><<<dim3(256), 512, 0, stream>>>(
        ctxb, wob, wob, wob, bo, bo, bo, nullptr, nullptr, nullptr, out);
}